// Round 6
// baseline (584.003 us; speedup 1.0000x reference)
//
#include <hip/hip_runtime.h>

#define NPTS 400000
#define KK 27
#define KP 28        // K padded to 4 batches of 7 (slice 27 is all-zero)
#define CC 32
#define EPSV 1e-5f
#define LSTRIDE 29   // odd stride -> conflict-free LDS access

using bf8_t = __attribute__((ext_vector_type(8))) __bf16;
using f4_t  = __attribute__((ext_vector_type(4))) float;
using us8_t = __attribute__((ext_vector_type(8))) unsigned short;

__device__ __forceinline__ unsigned short f2bf(float f) {
    unsigned int u = __float_as_uint(f);
    u += 0x7FFF + ((u >> 16) & 1u);   // RNE to bf16
    return (unsigned short)(u >> 16);
}

// ---------------------------------------------------------------------------
// Fused conversions: blocks [0,WBLOCKS) write W1|W2 -> bf16 [k][d][c] with a
// zeroed k=27 slice; remaining blocks convert x -> bf16 rows and append one
// all-zero sentinel row at index NPTS (masked gathers point here).
// ---------------------------------------------------------------------------
#define WBLOCKS 224  // 2*28*32*32 / 256
__global__ __launch_bounds__(256) void cvt_all(
    const float* __restrict__ x,
    const float* __restrict__ W1, const float* __restrict__ W2,
    unsigned short* __restrict__ xb,
    unsigned short* __restrict__ Wt1, unsigned short* __restrict__ Wt2)
{
    const int bid = blockIdx.x;
    if (bid < WBLOCKS) {
        const int id = bid * 256 + threadIdx.x;          // < 2*28*1024
        const int which = id >= KP * CC * CC;
        const int t = which ? id - KP * CC * CC : id;
        const int k = t >> 10, d = (t >> 5) & 31, c = t & 31;
        const float* W = which ? W2 : W1;
        unsigned short* Wt = which ? Wt2 : Wt1;
        Wt[t] = (k < KK) ? f2bf(W[k * 1024 + c * CC + d]) : (unsigned short)0;
        return;
    }
    const size_t base = ((size_t)(bid - WBLOCKS) * 256 + threadIdx.x) * 8;
    if (base >= (size_t)(NPTS + 1) * CC) return;
    if (base >= (size_t)NPTS * CC) {          // sentinel zero row
        us8_t z = {};
        *(us8_t*)(xb + base) = z;
        return;
    }
    const f4_t v0 = *(const f4_t*)(x + base);
    const f4_t v1 = *(const f4_t*)(x + base + 4);
    us8_t o;
#pragma unroll
    for (int j = 0; j < 8; ++j) o[j] = f2bf(j < 4 ? v0[j] : v1[j - 4]);
    *(us8_t*)(xb + base) = o;
}

// ---------------------------------------------------------------------------
// Gather-GEMM via MFMA, 2-stage software pipeline over 4 K-batches of 7.
// - nbr+mask staged in LDS as idx (masked -> sentinel NPTS): ALL gathers are
//   unconditional global_load_dwordx4 -> no exec-mask serialization, the
//   scheduler can keep a whole batch (14 loads/wave) in flight.
// - sched_barrier(0) pins the load-group / MFMA-group boundary (coarse).
// - Gather lands directly in A-frag layout: lane l loads 16B of row (l&15)
//   at byte offset (l>>4)*16; 4 lanes cover one 64B bf16 row.
// - Fused BN stats (sum, sumsq per channel) via shuffle + LDS + atomics.
// ---------------------------------------------------------------------------
__global__ __launch_bounds__(256, 3) void conv_mfma(
    const unsigned short* __restrict__ xb,   // [N+1][32] bf16 (row N = zeros)
    const unsigned short* __restrict__ Wt,   // [28][32(d)][32(c)] bf16
    const float* __restrict__ bias,          // [32]
    const int* __restrict__ nbr,             // [N][27]
    const int* __restrict__ mask,            // [N][27] int32 0/1
    float* __restrict__ out,                 // [N][32] fp32
    float* __restrict__ sums)                // [64]: sum, sumsq
{
    __shared__ int lidx[128 * LSTRIDE];      // 14848 B
    __shared__ float rs[4][CC], rq[4][CC];

    const int t = threadIdx.x;
    const int P0 = blockIdx.x * 128;         // 3125 blocks * 128 = N exactly

    // ---- stage fused indices (coalesced loads, conflict-free LDS) ----
    const int* nb = nbr + (size_t)P0 * KK;
    const int* mb = mask + (size_t)P0 * KK;
    for (int i = t; i < 128 * KK; i += 256) {
        const int p = i / KK;
        const int k = i - p * KK;
        lidx[p * LSTRIDE + k] = mb[i] ? nb[i] : NPTS;
    }
    if (t < 128) lidx[t * LSTRIDE + KK] = NPTS;   // padded k=27
    __syncthreads();

    const int wave = t >> 6;
    const int lane = t & 63;
    const int m = lane & 15;
    const int q = lane >> 4;
    const int p0 = P0 + wave * 32;

    const int* rowA = lidx + (wave * 32 + m) * LSTRIDE;
    const int* rowB = rowA + 16 * LSTRIDE;

    f4_t acc00 = {}, acc01 = {}, acc10 = {}, acc11 = {};
    bf8_t A0[7], A1[7], B0[7], B1[7];

#pragma unroll
    for (int j = 0; j < 7; ++j) {
        A0[j] = *(const bf8_t*)(xb + rowA[j] * CC + q * 8);
        A1[j] = *(const bf8_t*)(xb + rowB[j] * CC + q * 8);
    }

#pragma unroll
    for (int kb = 0; kb < 4; ++kb) {
        if (kb < 3) {
#pragma unroll
            for (int j = 0; j < 7; ++j) {
                B0[j] = *(const bf8_t*)(xb + rowA[(kb + 1) * 7 + j] * CC + q * 8);
                B1[j] = *(const bf8_t*)(xb + rowB[(kb + 1) * 7 + j] * CC + q * 8);
            }
        }
        __builtin_amdgcn_sched_barrier(0);
#pragma unroll
        for (int j = 0; j < 7; ++j) {
            const unsigned short* wk = Wt + (kb * 7 + j) * (CC * CC) + q * 8;
            const bf8_t w0 = *(const bf8_t*)(wk + m * CC);          // d 0..15
            const bf8_t w1 = *(const bf8_t*)(wk + (m + 16) * CC);   // d 16..31
            acc00 = __builtin_amdgcn_mfma_f32_16x16x32_bf16(A0[j], w0, acc00, 0, 0, 0);
            acc01 = __builtin_amdgcn_mfma_f32_16x16x32_bf16(A0[j], w1, acc01, 0, 0, 0);
            acc10 = __builtin_amdgcn_mfma_f32_16x16x32_bf16(A1[j], w0, acc10, 0, 0, 0);
            acc11 = __builtin_amdgcn_mfma_f32_16x16x32_bf16(A1[j], w1, acc11, 0, 0, 0);
        }
        __builtin_amdgcn_sched_barrier(0);
        if (kb < 3) {
#pragma unroll
            for (int j = 0; j < 7; ++j) { A0[j] = B0[j]; A1[j] = B1[j]; }
        }
    }

    // epilogue: D[row=(q*4+r)][col=m] -> point p0+16g+q*4+r, channel m(+16)
    const float b0 = bias[m], b1 = bias[m + 16];
    float s0 = 0.f, q0 = 0.f, s1 = 0.f, q1 = 0.f;
#pragma unroll
    for (int g = 0; g < 2; ++g) {
        const f4_t t0v = g ? acc10 : acc00;
        const f4_t t1v = g ? acc11 : acc01;
        const int prow = p0 + 16 * g + q * 4;
#pragma unroll
        for (int r = 0; r < 4; ++r) {
            const float v0 = t0v[r] + b0;
            const float v1 = t1v[r] + b1;
            out[(size_t)(prow + r) * CC + m] = v0;
            out[(size_t)(prow + r) * CC + m + 16] = v1;
            s0 += v0; q0 += v0 * v0;
            s1 += v1; q1 += v1 * v1;
        }
    }
    s0 += __shfl_down(s0, 32, 64); s0 += __shfl_down(s0, 16, 64);
    q0 += __shfl_down(q0, 32, 64); q0 += __shfl_down(q0, 16, 64);
    s1 += __shfl_down(s1, 32, 64); s1 += __shfl_down(s1, 16, 64);
    q1 += __shfl_down(q1, 32, 64); q1 += __shfl_down(q1, 16, 64);

    if (lane < 16) {
        rs[wave][m] = s0;      rq[wave][m] = q0;
        rs[wave][m + 16] = s1; rq[wave][m + 16] = q1;
    }
    __syncthreads();
    if (t < CC) {
        atomicAdd(&sums[t],      rs[0][t] + rs[1][t] + rs[2][t] + rs[3][t]);
        atomicAdd(&sums[CC + t], rq[0][t] + rq[1][t] + rq[2][t] + rq[3][t]);
    }
}

// ---------------------------------------------------------------------------
// BN + ReLU on fp32 h, write bf16 rows for conv2's gather.
// (Does NOT touch the sentinel row at index NPTS -- stays zero from cvt_all.)
// ---------------------------------------------------------------------------
__global__ __launch_bounds__(256) void bn_relu_bf16(
    const float* __restrict__ h, const float* __restrict__ sums,
    const float* __restrict__ gamma, const float* __restrict__ beta,
    unsigned short* __restrict__ buf)
{
    const size_t base = ((size_t)blockIdx.x * 256 + threadIdx.x) * 8;
    if (base >= (size_t)NPTS * CC) return;
    const int d0 = (int)(base & (CC - 1));
    const f4_t v0 = *(const f4_t*)(h + base);
    const f4_t v1 = *(const f4_t*)(h + base + 4);
    us8_t o;
#pragma unroll
    for (int j = 0; j < 8; ++j) {
        const int d = d0 + j;
        const float mean = sums[d] * (1.f / NPTS);
        const float var = sums[CC + d] * (1.f / NPTS) - mean * mean;
        const float sc = gamma[d] * rsqrtf(var + EPSV);
        const float x = (j < 4 ? v0[j] : v1[j - 4]);
        o[j] = f2bf(fmaxf((x - mean) * sc + beta[d], 0.f));
    }
    *(us8_t*)(buf + base) = o;
}

// ---------------------------------------------------------------------------
// BN + residual + ReLU, in place on d_out.
// ---------------------------------------------------------------------------
__global__ __launch_bounds__(256) void bn_res_relu_kernel(
    float* __restrict__ out, const float* __restrict__ sums,
    const float* __restrict__ gamma, const float* __restrict__ beta,
    const float* __restrict__ x)
{
    const size_t i = (size_t)blockIdx.x * 256 + threadIdx.x;
    const size_t base = i * 4;
    if (base >= (size_t)NPTS * CC) return;
    const int d0 = (int)(base & (CC - 1));
    float4 v = ((const float4*)out)[i];
    float4 rx = ((const float4*)x)[i];
    float r[4] = {v.x, v.y, v.z, v.w};
    const float rxf[4] = {rx.x, rx.y, rx.z, rx.w};
#pragma unroll
    for (int j = 0; j < 4; ++j) {
        const int d = d0 + j;
        const float mean = sums[d] * (1.f / NPTS);
        const float var = sums[CC + d] * (1.f / NPTS) - mean * mean;
        const float sc = gamma[d] * rsqrtf(var + EPSV);
        r[j] = fmaxf((r[j] - mean) * sc + beta[d] + rxf[j], 0.f);
    }
    ((float4*)out)[i] = make_float4(r[0], r[1], r[2], r[3]);
}

extern "C" void kernel_launch(void* const* d_in, const int* in_sizes, int n_in,
                              void* d_out, int out_size, void* d_ws, size_t ws_size,
                              hipStream_t stream) {
    const float* x   = (const float*)d_in[0];
    const float* W1  = (const float*)d_in[1];
    const float* b1  = (const float*)d_in[2];
    const float* g1  = (const float*)d_in[3];
    const float* be1 = (const float*)d_in[4];
    const float* W2  = (const float*)d_in[5];
    const float* b2  = (const float*)d_in[6];
    const float* g2  = (const float*)d_in[7];
    const float* be2 = (const float*)d_in[8];
    const int* nbr1  = (const int*)d_in[9];
    const int* mask1 = (const int*)d_in[10];
    const int* nbr2  = (const int*)d_in[11];
    const int* mask2 = (const int*)d_in[12];

    float* out = (float*)d_out;

    // workspace (~26 MB): sums | xbuf (bf16, N+1 rows, reused) | Wt1 | Wt2
    float* sums          = (float*)d_ws;                      // 256 floats
    unsigned short* xbuf = (unsigned short*)((char*)d_ws + 1024);
    unsigned short* Wt1  = xbuf + (size_t)(NPTS + 1) * CC;
    unsigned short* Wt2  = Wt1 + KP * CC * CC;

    hipMemsetAsync(d_ws, 0, 1024, stream);

    const int cvt_blocks = WBLOCKS + (int)(((size_t)(NPTS + 1) * CC / 8 + 255) / 256);

    cvt_all<<<cvt_blocks, 256, 0, stream>>>(x, W1, W2, xbuf, Wt1, Wt2);
    // conv1: h1 -> d_out (fp32) + stats in sums[0:64]
    conv_mfma<<<NPTS / 128, 256, 0, stream>>>(xbuf, Wt1, b1, nbr1, mask1, out, sums);
    // BN+ReLU -> bf16 xbuf (reuse; sentinel row untouched)
    bn_relu_bf16<<<(NPTS * CC / 8 + 255) / 256, 256, 0, stream>>>(out, sums, g1, be1, xbuf);
    // conv2: -> d_out (fp32) + stats in sums[64:128]
    conv_mfma<<<NPTS / 128, 256, 0, stream>>>(xbuf, Wt2, b2, nbr2, mask2, out, sums + 64);
    // BN + residual + ReLU in place
    bn_res_relu_kernel<<<(NPTS * CC / 4 + 255) / 256, 256, 0, stream>>>(out, sums + 64, g2, be2, x);
}